// Round 6
// baseline (280.755 us; speedup 1.0000x reference)
//
#include <hip/hip_runtime.h>
#include <stdint.h>

#define S_LEN 2048
#define DIM   1024
#define NH    16
#define HD    64
#define BATCH 4
#define M_ROWS (BATCH * S_LEN)  // 8192

typedef __attribute__((ext_vector_type(8))) __bf16 bf16x8;
typedef __attribute__((ext_vector_type(4))) float  f32x4;

union Frag { bf16x8 v; uint4 q; };

__device__ __forceinline__ ushort f2bf(float f) {
  union { float f; unsigned u; } x; x.f = f;
  unsigned r = x.u + 0x7fffu + ((x.u >> 16) & 1u);  // RNE
  return (ushort)(r >> 16);
}
// native cast (v_cvt_pk_bf16_f32 when paired)
__device__ __forceinline__ ushort f2bf_n(float f) {
  union { __bf16 b; ushort u; } x; x.b = (__bf16)f; return x.u;
}

__device__ __forceinline__ f32x4 mfma16(const Frag& a, const Frag& b, f32x4 c) {
  return __builtin_amdgcn_mfma_f32_16x16x32_bf16(a.v, b.v, c, 0, 0, 0);
}

// async global->LDS, 16B per lane; LDS dest = wave-uniform base + lane*16
__device__ __forceinline__ void gld_lds16(const ushort* g, ushort* l) {
  __builtin_amdgcn_global_load_lds(
      (__attribute__((address_space(1))) void*)g,
      (__attribute__((address_space(3))) void*)l, 16, 0, 0);
}

// ---------------- casts ----------------
__global__ void cast_x_kernel(const float* __restrict__ src, ushort* __restrict__ dst) {
  int i = blockIdx.x * 256 + threadIdx.x;
  float4 f = ((const float4*)src)[i];
  ushort4 u; u.x = f2bf(f.x); u.y = f2bf(f.y); u.z = f2bf(f.z); u.w = f2bf(f.w);
  ((ushort4*)dst)[i] = u;
}

__global__ void cast_w_kernel(const float* __restrict__ w0, const float* __restrict__ w1,
                              const float* __restrict__ w2, const float* __restrict__ w3,
                              ushort* __restrict__ d0, ushort* __restrict__ d1,
                              ushort* __restrict__ d2, ushort* __restrict__ d3) {
  const float* s; ushort* d;
  int z = blockIdx.y;
  if (z == 0) { s = w0; d = d0; } else if (z == 1) { s = w1; d = d1; }
  else if (z == 2) { s = w2; d = d2; } else { s = w3; d = d3; }
  int i = blockIdx.x * 256 + threadIdx.x;
  float4 f = ((const float4*)s)[i];
  ushort4 u; u.x = f2bf(f.x); u.y = f2bf(f.y); u.z = f2bf(f.z); u.w = f2bf(f.w);
  ((ushort4*)d)[i] = u;
}

// ---------------- 128x128 bt-GEMM, BK=64, XOR-swizzled LDS ----------------
// MODE 0: fused QKV.  grid (24,64): wsel=blockIdx.x>>3 picks Wq/Wk/Wv; writes
//         Q (scaled, [B,H,S,HD]) / K ([B,H,S,HD]) / V^T ([B,H,HD,S]).
// MODE 1: out-proj.   grid (8,64): f32 store out[m*DIM+e] + bias[e].
template <int MODE>
__global__ __launch_bounds__(256)
void gemm_bk64(const ushort* __restrict__ A,
               const ushort* __restrict__ B0, const ushort* __restrict__ B1,
               const ushort* __restrict__ B2,
               ushort* __restrict__ Qb, ushort* __restrict__ Kb, ushort* __restrict__ Vtb,
               float* __restrict__ outf, const float* __restrict__ bias, float scaleq) {
  __shared__ __align__(16) ushort As[128 * 64];
  __shared__ __align__(16) ushort Bs[128 * 64];
  const int K = DIM;
  int lane = threadIdx.x & 63, wave = threadIdx.x >> 6;
  int quad = lane >> 4, l15 = lane & 15;
  int rowBase = blockIdx.y * 128;
  int wsel, colBase;
  const ushort* Bt;
  if (MODE == 0) {
    wsel = blockIdx.x >> 3;
    colBase = (blockIdx.x & 7) * 128;
    Bt = (wsel == 0) ? B0 : (wsel == 1) ? B1 : B2;
  } else {
    wsel = 0;
    colBase = blockIdx.x * 128;
    Bt = B0;
  }
  int wm = (wave >> 1) * 64, wn = (wave & 1) * 64;

  const ushort* Ag = A + (size_t)rowBase * K;
  const ushort* Bg = Bt + (size_t)colBase * K;

  f32x4 acc[4][4];
#pragma unroll
  for (int i = 0; i < 4; i++)
#pragma unroll
    for (int j = 0; j < 4; j++) acc[i][j] = (f32x4){0.f, 0.f, 0.f, 0.f};

  for (int k0 = 0; k0 < K; k0 += 64) {
#pragma unroll
    for (int cc = 0; cc < 4; ++cc) {
      int c = wave * 4 + cc;                 // 16 chunks of 64 slots
      int s = c * 64 + lane;                 // 16B slot id in [0,1024)
      int row = s >> 3;
      int c8 = (s & 7) ^ (row & 7);          // swizzled chunk
      gld_lds16(Ag + (size_t)row * K + k0 + c8 * 8, &As[c * 512]);
      gld_lds16(Bg + (size_t)row * K + k0 + c8 * 8, &Bs[c * 512]);
    }
    __syncthreads();
    Frag af[4][2], bf[4][2];
#pragma unroll
    for (int t = 0; t < 4; t++) {
      int ar = wm + t * 16 + l15;
      int br = wn + t * 16 + l15;
#pragma unroll
      for (int kk = 0; kk < 2; kk++) {
        af[t][kk].q = *(const uint4*)&As[ar * 64 + (((kk * 4 + quad) ^ (ar & 7))) * 8];
        bf[t][kk].q = *(const uint4*)&Bs[br * 64 + (((kk * 4 + quad) ^ (br & 7))) * 8];
      }
    }
#pragma unroll
    for (int kk = 0; kk < 2; kk++)
#pragma unroll
      for (int i = 0; i < 4; i++)
#pragma unroll
        for (int j = 0; j < 4; j++) acc[i][j] = mfma16(af[i][kk], bf[j][kk], acc[i][j]);
    __syncthreads();
  }

#pragma unroll
  for (int i = 0; i < 4; i++) {
    int rowt = wm + i * 16 + quad * 4;
#pragma unroll
    for (int j = 0; j < 4; j++) {
      int e = colBase + wn + j * 16 + l15;  // within [0,1024)
      if (MODE == 0) {
        int h = e >> 6, hd = e & 63;
        if (wsel < 2) {
          ushort* dst = wsel ? Kb : Qb;
          float sc = wsel ? 1.f : scaleq;
#pragma unroll
          for (int r = 0; r < 4; r++) {
            int m = rowBase + rowt + r;
            int b = m >> 11, s = m & (S_LEN - 1);
            dst[((size_t)((b * NH + h) * S_LEN + s) << 6) + hd] = f2bf(acc[i][j][r] * sc);
          }
        } else {
          int m0 = rowBase + rowt;
          int b = m0 >> 11, s0 = m0 & (S_LEN - 1);
          ushort4 u;
          u.x = f2bf(acc[i][j][0]); u.y = f2bf(acc[i][j][1]);
          u.z = f2bf(acc[i][j][2]); u.w = f2bf(acc[i][j][3]);
          *(ushort4*)&Vtb[((size_t)((b * NH + h) * HD + hd) << 11) + s0] = u;
        }
      } else {
        float bv = bias[e];
#pragma unroll
        for (int r = 0; r < 4; r++) {
          int m = rowBase + rowt + r;
          outf[(size_t)m * DIM + e] = acc[i][j][r] + bv;
        }
      }
    }
  }
}

// ---------------- flash attention (causal; S^T orientation; no-max streaming softmax) ----------------
// v7: paired complementary q-tiles. R5 evidence: occupancy pinned ~19% across
// ALL resource configs -> cause is causal work imbalance + decaying residency,
// not resources. Each block now processes q-tiles qtA=15-pr AND qtB=pr:
//  * every block runs exactly 17 compute-iterations -> uniform durations, no
//    tail; grid 512 blocks = 2 blocks/CU, 8 waves/CU steady.
//  * K/V staged once per kt serves BOTH tiles while kt<=qtB: grid-wide tile
//    stagings drop 136->100 per bh (-26% staging traffic, compute unchanged).
//  * per-tile inner pipeline is R5's verified code (de-fused MFMA burst ->
//    mask -> exp2/pack -> permlane redistribute -> PV + ones-MFMA l-trick);
//    tile B reuses the sacc/sw/pf transients sequentially.
//  * prologue stages Q_A into Ks and Q_B into Vs concurrently.
// grid (B*H, 8).
__global__ __launch_bounds__(256)
void flash_attn(const ushort* __restrict__ Qb, const ushort* __restrict__ Kb,
                const ushort* __restrict__ Vtb, ushort* __restrict__ Ctx) {
  __shared__ __align__(16) ushort Ks[128 * 64];   // K tile (also Q_A staging), swizzled
  __shared__ __align__(16) ushort Vs[64 * 128];   // V^T tile (also Q_B staging), swizzled

  int lane = threadIdx.x & 63, wave = threadIdx.x >> 6;
  int quad = lane >> 4, l15 = lane & 15;
  int bh = blockIdx.x;
  int pr = blockIdx.y;                 // 0..7
  int qtA = 15 - pr, qtB = pr;         // disjoint: qtA in [8,15], qtB in [0,7]
  int q0A = qtA * 128, q0B = qtB * 128, wq0 = wave * 32;

  const ushort* Qh = Qb + (size_t)bh * S_LEN * HD;
  const ushort* Kh = Kb + (size_t)bh * S_LEN * HD;
  const ushort* Vh = Vtb + (size_t)bh * HD * S_LEN;

  // ---- prologue: stage Q_A -> Ks and Q_B -> Vs (same swizzled layout)
#pragma unroll
  for (int cc = 0; cc < 4; ++cc) {
    int c = wave * 4 + cc;
    int s = c * 64 + lane;
    int row = s >> 3;
    int c8 = (s & 7) ^ (row & 7);
    gld_lds16(Qh + (size_t)(q0A + row) * HD + c8 * 8, &Ks[c * 512]);
    gld_lds16(Qh + (size_t)(q0B + row) * HD + c8 * 8, &Vs[c * 512]);
  }
  __syncthreads();
  Frag qfA[2][2], qfB[2][2];  // B-frag: B[d][qrow]
#pragma unroll
  for (int it = 0; it < 2; ++it)
#pragma unroll
    for (int ks = 0; ks < 2; ++ks) {
      int row = wq0 + it * 16 + l15;
      int c8 = (ks * 4 + quad) ^ (row & 7);
      qfA[it][ks].q = *(const uint4*)&Ks[row * 64 + c8 * 8];
      qfB[it][ks].q = *(const uint4*)&Vs[row * 64 + c8 * 8];
    }
  __syncthreads();  // qf readers done before kt=0 staging overwrites Ks/Vs

  Frag onesf;  // all-ones bf16 B-frag for the l-via-MFMA trick
  onesf.q = (uint4){0x3F803F80u, 0x3F803F80u, 0x3F803F80u, 0x3F803F80u};

  f32x4 laccA[2], laccB[2];
  f32x4 oaccA[2][4], oaccB[2][4];
#pragma unroll
  for (int it = 0; it < 2; ++it) {
    laccA[it] = (f32x4){0.f, 0.f, 0.f, 0.f};
    laccB[it] = (f32x4){0.f, 0.f, 0.f, 0.f};
#pragma unroll
    for (int dt = 0; dt < 4; ++dt) {
      oaccA[it][dt] = (f32x4){0.f, 0.f, 0.f, 0.f};
      oaccB[it][dt] = (f32x4){0.f, 0.f, 0.f, 0.f};
    }
  }

  // ---- per-tile pipeline (R5's verified structure), inlined via lambda
  auto attn_tile = [&](const Frag (&qf)[2][2], f32x4 (&oacc)[2][4],
                       f32x4 (&lacc)[2], bool diag) {
    // S^T = K · Q^T: pure MFMA burst (16 independent chains)
    f32x4 sacc[2][8];
    __builtin_amdgcn_s_setprio(1);
#pragma unroll
    for (int jt = 0; jt < 8; ++jt) {
      int row = jt * 16 + l15;
      Frag kf0, kf1;
      kf0.q = *(const uint4*)&Ks[row * 64 + ((quad ^ (row & 7))) * 8];
      kf1.q = *(const uint4*)&Ks[row * 64 + (((4 + quad) ^ (row & 7))) * 8];
#pragma unroll
      for (int it = 0; it < 2; ++it) {
        f32x4 a = (f32x4){0.f, 0.f, 0.f, 0.f};
        a = mfma16(kf0, qf[it][0], a);
        a = mfma16(kf1, qf[it][1], a);
        sacc[it][jt] = a;
      }
    }
    __builtin_amdgcn_s_setprio(0);

    // causal mask (diagonal tile only)
    if (diag) {
#pragma unroll
      for (int it = 0; it < 2; ++it)
#pragma unroll
        for (int jt = 0; jt < 8; ++jt)
#pragma unroll
          for (int r = 0; r < 4; ++r)
            if (jt * 16 + quad * 4 + r > wq0 + it * 16 + l15)
              sacc[it][jt][r] = -1e30f;
    }

    // exp2 + pack burst (no sum: l comes from the ones-MFMA below)
    uint sw[2][8][2];
#pragma unroll
    for (int it = 0; it < 2; ++it)
#pragma unroll
      for (int jt = 0; jt < 8; ++jt) {
        float p0 = exp2f(sacc[it][jt][0]);
        float p1 = exp2f(sacc[it][jt][1]);
        float p2 = exp2f(sacc[it][jt][2]);
        float p3 = exp2f(sacc[it][jt][3]);
        union { ushort2 h; uint u; } w0, w1;
        w0.h.x = f2bf_n(p0); w0.h.y = f2bf_n(p1);
        w1.h.x = f2bf_n(p2); w1.h.y = f2bf_n(p3);
        sw[it][jt][0] = w0.u;
        sw[it][jt][1] = w1.u;
      }

    // in-register P redistribution via permlane swaps (verified lane algebra)
    Frag pf[2][4];
#pragma unroll
    for (int it = 0; it < 2; ++it)
#pragma unroll
      for (int ks = 0; ks < 4; ++ks) {
        uint x0 = sw[it][2 * ks][0], y0 = sw[it][2 * ks + 1][0];
        uint x1 = sw[it][2 * ks][1], y1 = sw[it][2 * ks + 1][1];
        asm("v_permlane32_swap_b32 %0, %1" : "+v"(x0), "+v"(y0));
        asm("v_permlane16_swap_b32 %0, %1" : "+v"(x0), "+v"(y0));
        asm("v_permlane32_swap_b32 %0, %1" : "+v"(x1), "+v"(y1));
        asm("v_permlane16_swap_b32 %0, %1" : "+v"(x1), "+v"(y1));
        pf[it][ks].q = (uint4){x0, x1, y0, y1};
      }

    // O += P V  and  l += P · 1 (V frags shared across both q sub-tiles)
    __builtin_amdgcn_s_setprio(1);
#pragma unroll
    for (int dt = 0; dt < 4; ++dt) {
      int row = dt * 16 + l15;
      Frag vf[4];
#pragma unroll
      for (int ks = 0; ks < 4; ++ks)
        vf[ks].q = *(const uint4*)&Vs[row * 128 + (((ks * 4 + quad) ^ (row & 15))) * 8];
#pragma unroll
      for (int it = 0; it < 2; ++it) {
        f32x4 a = oacc[it][dt];
#pragma unroll
        for (int ks = 0; ks < 4; ++ks) a = mfma16(pf[it][ks], vf[ks], a);
        oacc[it][dt] = a;
      }
    }
#pragma unroll
    for (int it = 0; it < 2; ++it) {
      f32x4 a = lacc[it];
#pragma unroll
      for (int ks = 0; ks < 4; ++ks) a = mfma16(pf[it][ks], onesf, a);
      lacc[it] = a;
    }
    __builtin_amdgcn_s_setprio(0);
  };

  for (int kt = 0; kt <= qtA; ++kt) {
    // ---- stage K (8 slots/row) and V^T (16 slots/row), both XOR-swizzled
#pragma unroll
    for (int cc = 0; cc < 4; ++cc) {
      int c = wave * 4 + cc;
      int s = c * 64 + lane;
      int krow = s >> 3, kc8 = (s & 7) ^ (krow & 7);
      int vrow = s >> 4, vc8 = (s & 15) ^ (vrow & 15);
      gld_lds16(Kh + (size_t)(kt * 128 + krow) * HD + kc8 * 8, &Ks[c * 512]);
      gld_lds16(Vh + (size_t)vrow * S_LEN + kt * 128 + vc8 * 8, &Vs[c * 512]);
    }
    __syncthreads();

    attn_tile(qfA, oaccA, laccA, kt == qtA);          // tile A: always active
    if (kt <= qtB) attn_tile(qfB, oaccB, laccB, kt == qtB);  // tile B: prefix only

    __syncthreads();  // all waves done with Ks/Vs before restage
  }

  // ---- epilogue: normalize by l (lacc[it][r] = l[q], uniform over l15)
  int b = bh >> 4, h = bh & 15;
  auto store_tile = [&](int q0, f32x4 (&oacc)[2][4], f32x4 (&lacc)[2]) {
#pragma unroll
    for (int it = 0; it < 2; ++it) {
      float lr[4];
#pragma unroll
      for (int r = 0; r < 4; ++r) lr[r] = 1.f / lacc[it][r];
#pragma unroll
      for (int r = 0; r < 4; ++r) {
        int qg = q0 + wq0 + it * 16 + quad * 4 + r;
        size_t base = ((size_t)(b * S_LEN + qg)) * DIM + h * HD;
#pragma unroll
        for (int dt = 0; dt < 4; ++dt)
          Ctx[base + dt * 16 + l15] = f2bf_n(oacc[it][dt][r] * lr[r]);
      }
    }
  };
  store_tile(q0A, oaccA, laccA);
  store_tile(q0B, oaccB, laccB);
}

// ---------------- launch ----------------
extern "C" void kernel_launch(void* const* d_in, const int* in_sizes, int n_in,
                              void* d_out, int out_size, void* d_ws, size_t ws_size,
                              hipStream_t stream) {
  (void)in_sizes; (void)n_in; (void)out_size; (void)ws_size;
  const float* x  = (const float*)d_in[0];
  const float* Wq = (const float*)d_in[1];
  const float* Wk = (const float*)d_in[2];
  const float* Wv = (const float*)d_in[3];
  const float* Wo = (const float*)d_in[4];
  const float* bo = (const float*)d_in[5];
  float* out = (float*)d_out;

  ushort* Xb  = (ushort*)d_ws;                     // [8192][1024]
  ushort* Wqb = Xb  + (size_t)M_ROWS * DIM;
  ushort* Wkb = Wqb + (size_t)DIM * DIM;
  ushort* Wvb = Wkb + (size_t)DIM * DIM;
  ushort* Wob = Wvb + (size_t)DIM * DIM;
  ushort* Qb  = Wob + (size_t)DIM * DIM;           // [B,H,S,HD] (pre-scaled)
  ushort* Kb  = Qb  + (size_t)M_ROWS * DIM;        // [B,H,S,HD]
  ushort* Vtb = Kb  + (size_t)M_ROWS * DIM;        // [B,H,HD,S]
  ushort* Ctx = Vtb + (size_t)M_ROWS * DIM;        // [B,S,D]

  const float SCALE_Q = 0.18033688011112042f;  // log2(e) / sqrt(HD)

  cast_x_kernel<<<dim3(M_ROWS * DIM / 1024), 256, 0, stream>>>(x, Xb);
  cast_w_kernel<<<dim3(DIM * DIM / 1024, 4), 256, 0, stream>>>(Wq, Wk, Wv, Wo, Wqb, Wkb, Wvb, Wob);

  gemm_bk64<0><<<dim3(24, 64), 256, 0, stream>>>(Xb, Wqb, Wkb, Wvb, Qb, Kb, Vtb,
                                                 nullptr, nullptr, SCALE_Q);

  flash_attn<<<dim3(BATCH * NH, 8), 256, 0, stream>>>(Qb, Kb, Vtb, Ctx);

  gemm_bk64<1><<<dim3(8, 64), 256, 0, stream>>>(Ctx, Wob, nullptr, nullptr, nullptr, nullptr,
                                                nullptr, out, bo, 1.0f);
}

// Round 7
// 278.249 us; speedup vs baseline: 1.0090x; 1.0090x over previous
//
#include <hip/hip_runtime.h>
#include <stdint.h>

#define S_LEN 2048
#define DIM   1024
#define NH    16
#define HD    64
#define BATCH 4
#define M_ROWS (BATCH * S_LEN)  // 8192

typedef __attribute__((ext_vector_type(8))) __bf16 bf16x8;
typedef __attribute__((ext_vector_type(4))) float  f32x4;

union Frag { bf16x8 v; uint4 q; };

__device__ __forceinline__ ushort f2bf(float f) {
  union { float f; unsigned u; } x; x.f = f;
  unsigned r = x.u + 0x7fffu + ((x.u >> 16) & 1u);  // RNE
  return (ushort)(r >> 16);
}
// native cast (v_cvt_pk_bf16_f32 when paired)
__device__ __forceinline__ ushort f2bf_n(float f) {
  union { __bf16 b; ushort u; } x; x.b = (__bf16)f; return x.u;
}

__device__ __forceinline__ f32x4 mfma16(const Frag& a, const Frag& b, f32x4 c) {
  return __builtin_amdgcn_mfma_f32_16x16x32_bf16(a.v, b.v, c, 0, 0, 0);
}

// async global->LDS, 16B per lane; LDS dest = wave-uniform base + lane*16
__device__ __forceinline__ void gld_lds16(const ushort* g, ushort* l) {
  __builtin_amdgcn_global_load_lds(
      (__attribute__((address_space(1))) void*)g,
      (__attribute__((address_space(3))) void*)l, 16, 0, 0);
}

// ---------------- weight cast ----------------
__global__ void cast_w_kernel(const float* __restrict__ w0, const float* __restrict__ w1,
                              const float* __restrict__ w2, const float* __restrict__ w3,
                              ushort* __restrict__ d0, ushort* __restrict__ d1,
                              ushort* __restrict__ d2, ushort* __restrict__ d3) {
  const float* s; ushort* d;
  int z = blockIdx.y;
  if (z == 0) { s = w0; d = d0; } else if (z == 1) { s = w1; d = d1; }
  else if (z == 2) { s = w2; d = d2; } else { s = w3; d = d3; }
  int i = blockIdx.x * 256 + threadIdx.x;
  float4 f = ((const float4*)s)[i];
  ushort4 u; u.x = f2bf(f.x); u.y = f2bf(f.y); u.z = f2bf(f.z); u.w = f2bf(f.w);
  ((ushort4*)d)[i] = u;
}

// ---------------- 128x128 bt-GEMM, BK=64, XOR-swizzled LDS ----------------
// MODE 0: fused QKV.  grid (24,64): wsel=blockIdx.x>>3 picks Wq/Wk/Wv; writes
//         Q (scaled, [B,H,S,HD]) / K ([B,H,S,HD]) / V^T ([B,H,HD,S]).
//         A-side reads f32 X DIRECTLY (inline cast + ds_write staging; the
//         standalone cast_x kernel and the Xb round-trip are gone).
// MODE 1: out-proj.   grid (8,64): bf16 A via global_load_lds; f32 store
//         out[m*DIM+e] + bias[e].
template <int MODE>
__global__ __launch_bounds__(256)
void gemm_bk64(const ushort* __restrict__ A, const float* __restrict__ Af,
               const ushort* __restrict__ B0, const ushort* __restrict__ B1,
               const ushort* __restrict__ B2,
               ushort* __restrict__ Qb, ushort* __restrict__ Kb, ushort* __restrict__ Vtb,
               float* __restrict__ outf, const float* __restrict__ bias, float scaleq) {
  __shared__ __align__(16) ushort As[128 * 64];
  __shared__ __align__(16) ushort Bs[128 * 64];
  const int K = DIM;
  int lane = threadIdx.x & 63, wave = threadIdx.x >> 6;
  int quad = lane >> 4, l15 = lane & 15;
  int rowBase = blockIdx.y * 128;
  int wsel, colBase;
  const ushort* Bt;
  if (MODE == 0) {
    wsel = blockIdx.x >> 3;
    colBase = (blockIdx.x & 7) * 128;
    Bt = (wsel == 0) ? B0 : (wsel == 1) ? B1 : B2;
  } else {
    wsel = 0;
    colBase = blockIdx.x * 128;
    Bt = B0;
  }
  int wm = (wave >> 1) * 64, wn = (wave & 1) * 64;

  const ushort* Ag = A + (size_t)rowBase * K;       // MODE 1 path
  const float*  Ax = Af + (size_t)rowBase * K;      // MODE 0 path
  const ushort* Bg = Bt + (size_t)colBase * K;

  f32x4 acc[4][4];
#pragma unroll
  for (int i = 0; i < 4; i++)
#pragma unroll
    for (int j = 0; j < 4; j++) acc[i][j] = (f32x4){0.f, 0.f, 0.f, 0.f};

  for (int k0 = 0; k0 < K; k0 += 64) {
#pragma unroll
    for (int cc = 0; cc < 4; ++cc) {
      int c = wave * 4 + cc;                 // 16 chunks of 64 slots
      int s = c * 64 + lane;                 // 16B slot id in [0,1024)
      int row = s >> 3;
      int c8 = (s & 7) ^ (row & 7);          // swizzled chunk
      if (MODE == 0) {
        // inline f32->bf16 cast staging; same slot algebra as gld_lds
        // (dest ushort offset s*8 == c*512 + lane*8)
        const float* src = Ax + (size_t)row * K + k0 + c8 * 8;
        float4 f0 = *(const float4*)src;
        float4 f1 = *(const float4*)(src + 4);
        union { ushort u[8]; uint4 q; } w;
        w.u[0] = f2bf_n(f0.x); w.u[1] = f2bf_n(f0.y);
        w.u[2] = f2bf_n(f0.z); w.u[3] = f2bf_n(f0.w);
        w.u[4] = f2bf_n(f1.x); w.u[5] = f2bf_n(f1.y);
        w.u[6] = f2bf_n(f1.z); w.u[7] = f2bf_n(f1.w);
        *(uint4*)&As[s * 8] = w.q;
      } else {
        gld_lds16(Ag + (size_t)row * K + k0 + c8 * 8, &As[c * 512]);
      }
      gld_lds16(Bg + (size_t)row * K + k0 + c8 * 8, &Bs[c * 512]);
    }
    __syncthreads();
    Frag af[4][2], bf[4][2];
#pragma unroll
    for (int t = 0; t < 4; t++) {
      int ar = wm + t * 16 + l15;
      int br = wn + t * 16 + l15;
#pragma unroll
      for (int kk = 0; kk < 2; kk++) {
        af[t][kk].q = *(const uint4*)&As[ar * 64 + (((kk * 4 + quad) ^ (ar & 7))) * 8];
        bf[t][kk].q = *(const uint4*)&Bs[br * 64 + (((kk * 4 + quad) ^ (br & 7))) * 8];
      }
    }
#pragma unroll
    for (int kk = 0; kk < 2; kk++)
#pragma unroll
      for (int i = 0; i < 4; i++)
#pragma unroll
        for (int j = 0; j < 4; j++) acc[i][j] = mfma16(af[i][kk], bf[j][kk], acc[i][j]);
    __syncthreads();
  }

#pragma unroll
  for (int i = 0; i < 4; i++) {
    int rowt = wm + i * 16 + quad * 4;
#pragma unroll
    for (int j = 0; j < 4; j++) {
      int e = colBase + wn + j * 16 + l15;  // within [0,1024)
      if (MODE == 0) {
        int h = e >> 6, hd = e & 63;
        if (wsel < 2) {
          ushort* dst = wsel ? Kb : Qb;
          float sc = wsel ? 1.f : scaleq;
#pragma unroll
          for (int r = 0; r < 4; r++) {
            int m = rowBase + rowt + r;
            int b = m >> 11, s = m & (S_LEN - 1);
            dst[((size_t)((b * NH + h) * S_LEN + s) << 6) + hd] = f2bf_n(acc[i][j][r] * sc);
          }
        } else {
          int m0 = rowBase + rowt;
          int b = m0 >> 11, s0 = m0 & (S_LEN - 1);
          ushort4 u;
          u.x = f2bf_n(acc[i][j][0]); u.y = f2bf_n(acc[i][j][1]);
          u.z = f2bf_n(acc[i][j][2]); u.w = f2bf_n(acc[i][j][3]);
          *(ushort4*)&Vtb[((size_t)((b * NH + h) * HD + hd) << 11) + s0] = u;
        }
      } else {
        float bv = bias[e];
#pragma unroll
        for (int r = 0; r < 4; r++) {
          int m = rowBase + rowt + r;
          outf[(size_t)m * DIM + e] = acc[i][j][r] + bv;
        }
      }
    }
  }
}

// ---------------- flash attention (causal; S^T orientation; no-max streaming softmax) ----------------
// v8 == R5's verified kernel (81.6 us), reverted verbatim. R6's paired-tile
// variant halved residency (VGPR 172 crossed the 128 cliff; occupancy 19->10.5%)
// and regressed 22%; R5 is the measured optimum of this structure.
//  * de-fused pipeline: 16-MFMA S^T burst -> mask -> exp2/pack burst ->
//    permlane P-redistribution (in-register, zero DS ops) -> PV MFMA burst.
//  * softmax denominator via ones-MFMA (l = P x 1), no VALU reduction.
//  * single-buffered 32 KiB LDS; plain __launch_bounds__(256) (VGPR 124, no
//    spills); bank conflicts measured 0.
//  * bijective balanced qt map {15-yr, 8+yr, 4+yr, 3-yr}.
// grid (B*H, S/128).
__global__ __launch_bounds__(256)
void flash_attn(const ushort* __restrict__ Qb, const ushort* __restrict__ Kb,
                const ushort* __restrict__ Vtb, ushort* __restrict__ Ctx) {
  __shared__ __align__(16) ushort Ks[128 * 64];   // K tile (also Q staging), swizzled
  __shared__ __align__(16) ushort Vs[64 * 128];   // V^T tile, swizzled

  int lane = threadIdx.x & 63, wave = threadIdx.x >> 6;
  int quad = lane >> 4, l15 = lane & 15;
  int bh = blockIdx.x;
  int yq = blockIdx.y >> 2, yr = blockIdx.y & 3;
  int qt = (yq == 0) ? (15 - yr) : (yq == 1) ? (8 + yr) : (yq == 2) ? (4 + yr) : (3 - yr);
  int q0 = qt * 128, wq0 = wave * 32;

  const ushort* Qh = Qb + (size_t)bh * S_LEN * HD;
  const ushort* Kh = Kb + (size_t)bh * S_LEN * HD;
  const ushort* Vh = Vtb + (size_t)bh * HD * S_LEN;

  // ---- stage Q tile (swizzled) into Ks, pull B-frags into registers
#pragma unroll
  for (int cc = 0; cc < 4; ++cc) {
    int c = wave * 4 + cc;
    int s = c * 64 + lane;
    int row = s >> 3;
    int c8 = (s & 7) ^ (row & 7);
    gld_lds16(Qh + (size_t)(q0 + row) * HD + c8 * 8, &Ks[c * 512]);
  }
  __syncthreads();
  Frag qf[2][2];  // B-frag: B[d][qrow]
#pragma unroll
  for (int it = 0; it < 2; ++it)
#pragma unroll
    for (int ks = 0; ks < 2; ++ks) {
      int row = wq0 + it * 16 + l15;
      int c8 = (ks * 4 + quad) ^ (row & 7);
      qf[it][ks].q = *(const uint4*)&Ks[row * 64 + c8 * 8];
    }
  __syncthreads();  // qf readers done before kt=0 staging overwrites Ks

  Frag onesf;  // all-ones bf16 B-frag for the l-via-MFMA trick
  onesf.q = (uint4){0x3F803F80u, 0x3F803F80u, 0x3F803F80u, 0x3F803F80u};

  f32x4 lacc[2];
  f32x4 oacc[2][4];
#pragma unroll
  for (int it = 0; it < 2; ++it) {
    lacc[it] = (f32x4){0.f, 0.f, 0.f, 0.f};
#pragma unroll
    for (int dt = 0; dt < 4; ++dt) oacc[it][dt] = (f32x4){0.f, 0.f, 0.f, 0.f};
  }

  for (int kt = 0; kt <= qt; ++kt) {
    // ---- stage K (8 slots/row) and V^T (16 slots/row), both XOR-swizzled
#pragma unroll
    for (int cc = 0; cc < 4; ++cc) {
      int c = wave * 4 + cc;
      int s = c * 64 + lane;
      int krow = s >> 3, kc8 = (s & 7) ^ (krow & 7);
      int vrow = s >> 4, vc8 = (s & 15) ^ (vrow & 15);
      gld_lds16(Kh + (size_t)(kt * 128 + krow) * HD + kc8 * 8, &Ks[c * 512]);
      gld_lds16(Vh + (size_t)vrow * S_LEN + kt * 128 + vc8 * 8, &Vs[c * 512]);
    }
    __syncthreads();

    // ---- S^T = K · Q^T: pure MFMA burst (16 independent chains, pipelined)
    f32x4 sacc[2][8];
    __builtin_amdgcn_s_setprio(1);
#pragma unroll
    for (int jt = 0; jt < 8; ++jt) {
      int row = jt * 16 + l15;
      Frag kf0, kf1;
      kf0.q = *(const uint4*)&Ks[row * 64 + ((quad ^ (row & 7))) * 8];
      kf1.q = *(const uint4*)&Ks[row * 64 + (((4 + quad) ^ (row & 7))) * 8];
#pragma unroll
      for (int it = 0; it < 2; ++it) {
        f32x4 a = (f32x4){0.f, 0.f, 0.f, 0.f};
        a = mfma16(kf0, qf[it][0], a);
        a = mfma16(kf1, qf[it][1], a);
        sacc[it][jt] = a;
      }
    }
    __builtin_amdgcn_s_setprio(0);

    // ---- causal mask on the diagonal tile only
    if (kt == qt) {
#pragma unroll
      for (int it = 0; it < 2; ++it)
#pragma unroll
        for (int jt = 0; jt < 8; ++jt)
#pragma unroll
          for (int r = 0; r < 4; ++r)
            if (jt * 16 + quad * 4 + r > wq0 + it * 16 + l15)
              sacc[it][jt][r] = -1e30f;
    }

    // ---- exp2 + pack burst (no sum: l comes from the ones-MFMA below)
    uint sw[2][8][2];
#pragma unroll
    for (int it = 0; it < 2; ++it)
#pragma unroll
      for (int jt = 0; jt < 8; ++jt) {
        float p0 = exp2f(sacc[it][jt][0]);
        float p1 = exp2f(sacc[it][jt][1]);
        float p2 = exp2f(sacc[it][jt][2]);
        float p3 = exp2f(sacc[it][jt][3]);
        union { ushort2 h; uint u; } w0, w1;
        w0.h.x = f2bf_n(p0); w0.h.y = f2bf_n(p1);
        w1.h.x = f2bf_n(p2); w1.h.y = f2bf_n(p3);
        sw[it][jt][0] = w0.u;
        sw[it][jt][1] = w1.u;
      }

    // ---- in-register P redistribution: quads exchange at fixed l15.
    // x=[X0 X1 X2 X3] (by quad), y=[Y0..Y3]; after 32-swap: x'=[X0 X1 Y0 Y1],
    // y'=[X2 X3 Y2 Y3]; after 16-swap: x''=[X0 X2 Y0 Y2] (A-frag word u),
    // y''=[X1 X3 Y1 Y3] (A-frag word 2+u).
    Frag pf[2][4];
#pragma unroll
    for (int it = 0; it < 2; ++it)
#pragma unroll
      for (int ks = 0; ks < 4; ++ks) {
        uint x0 = sw[it][2 * ks][0], y0 = sw[it][2 * ks + 1][0];
        uint x1 = sw[it][2 * ks][1], y1 = sw[it][2 * ks + 1][1];
        asm("v_permlane32_swap_b32 %0, %1" : "+v"(x0), "+v"(y0));
        asm("v_permlane16_swap_b32 %0, %1" : "+v"(x0), "+v"(y0));
        asm("v_permlane32_swap_b32 %0, %1" : "+v"(x1), "+v"(y1));
        asm("v_permlane16_swap_b32 %0, %1" : "+v"(x1), "+v"(y1));
        pf[it][ks].q = (uint4){x0, x1, y0, y1};
      }

    // ---- O += P V  and  l += P · 1 (ones-MFMA; V frags shared across its)
    __builtin_amdgcn_s_setprio(1);
#pragma unroll
    for (int dt = 0; dt < 4; ++dt) {
      int row = dt * 16 + l15;
      Frag vf[4];
#pragma unroll
      for (int ks = 0; ks < 4; ++ks)
        vf[ks].q = *(const uint4*)&Vs[row * 128 + (((ks * 4 + quad) ^ (row & 15))) * 8];
#pragma unroll
      for (int it = 0; it < 2; ++it) {
        f32x4 a = oacc[it][dt];
#pragma unroll
        for (int ks = 0; ks < 4; ++ks) a = mfma16(pf[it][ks], vf[ks], a);
        oacc[it][dt] = a;
      }
    }
#pragma unroll
    for (int it = 0; it < 2; ++it) {
      f32x4 a = lacc[it];
#pragma unroll
      for (int ks = 0; ks < 4; ++ks) a = mfma16(pf[it][ks], onesf, a);
      lacc[it] = a;
    }
    __builtin_amdgcn_s_setprio(0);

    __syncthreads();  // all waves done with Ks/Vs before restage
  }

  // ---- epilogue: normalize by l (lacc[it][r] = l[q], uniform over l15)
  int b = bh >> 4, h = bh & 15;
#pragma unroll
  for (int it = 0; it < 2; ++it) {
    float lr[4];
#pragma unroll
    for (int r = 0; r < 4; ++r) lr[r] = 1.f / lacc[it][r];
#pragma unroll
    for (int r = 0; r < 4; ++r) {
      int qg = q0 + wq0 + it * 16 + quad * 4 + r;
      size_t base = ((size_t)(b * S_LEN + qg)) * DIM + h * HD;
#pragma unroll
      for (int dt = 0; dt < 4; ++dt)
        Ctx[base + dt * 16 + l15] = f2bf_n(oacc[it][dt][r] * lr[r]);
    }
  }
}

// ---------------- launch ----------------
extern "C" void kernel_launch(void* const* d_in, const int* in_sizes, int n_in,
                              void* d_out, int out_size, void* d_ws, size_t ws_size,
                              hipStream_t stream) {
  (void)in_sizes; (void)n_in; (void)out_size; (void)ws_size;
  const float* x  = (const float*)d_in[0];
  const float* Wq = (const float*)d_in[1];
  const float* Wk = (const float*)d_in[2];
  const float* Wv = (const float*)d_in[3];
  const float* Wo = (const float*)d_in[4];
  const float* bo = (const float*)d_in[5];
  float* out = (float*)d_out;

  ushort* Xb  = (ushort*)d_ws;                     // (unused slot kept for layout stability)
  ushort* Wqb = Xb  + (size_t)M_ROWS * DIM;
  ushort* Wkb = Wqb + (size_t)DIM * DIM;
  ushort* Wvb = Wkb + (size_t)DIM * DIM;
  ushort* Wob = Wvb + (size_t)DIM * DIM;
  ushort* Qb  = Wob + (size_t)DIM * DIM;           // [B,H,S,HD] (pre-scaled)
  ushort* Kb  = Qb  + (size_t)M_ROWS * DIM;        // [B,H,S,HD]
  ushort* Vtb = Kb  + (size_t)M_ROWS * DIM;        // [B,H,HD,S]
  ushort* Ctx = Vtb + (size_t)M_ROWS * DIM;        // [B,S,D]

  const float SCALE_Q = 0.18033688011112042f;  // log2(e) / sqrt(HD)

  cast_w_kernel<<<dim3(DIM * DIM / 1024, 4), 256, 0, stream>>>(Wq, Wk, Wv, Wo, Wqb, Wkb, Wvb, Wob);

  gemm_bk64<0><<<dim3(24, 64), 256, 0, stream>>>(nullptr, x, Wqb, Wkb, Wvb,
                                                 Qb, Kb, Vtb, nullptr, nullptr, SCALE_Q);

  flash_attn<<<dim3(BATCH * NH, S_LEN / 128), 256, 0, stream>>>(Qb, Kb, Vtb, Ctx);

  gemm_bk64<1><<<dim3(8, 64), 256, 0, stream>>>(Ctx, nullptr, Wob, nullptr, nullptr,
                                                nullptr, nullptr, nullptr, out, bo, 1.0f);
}

// Round 8
// 262.944 us; speedup vs baseline: 1.0677x; 1.0582x over previous
//
#include <hip/hip_runtime.h>
#include <stdint.h>

#define S_LEN 2048
#define DIM   1024
#define NH    16
#define HD    64
#define BATCH 4
#define M_ROWS (BATCH * S_LEN)  // 8192

typedef __attribute__((ext_vector_type(8))) __bf16 bf16x8;
typedef __attribute__((ext_vector_type(4))) float  f32x4;

union Frag { bf16x8 v; uint4 q; };

__device__ __forceinline__ ushort f2bf(float f) {
  union { float f; unsigned u; } x; x.f = f;
  unsigned r = x.u + 0x7fffu + ((x.u >> 16) & 1u);  // RNE
  return (ushort)(r >> 16);
}
// native cast (v_cvt_pk_bf16_f32 when paired)
__device__ __forceinline__ ushort f2bf_n(float f) {
  union { __bf16 b; ushort u; } x; x.b = (__bf16)f; return x.u;
}

__device__ __forceinline__ f32x4 mfma16(const Frag& a, const Frag& b, f32x4 c) {
  return __builtin_amdgcn_mfma_f32_16x16x32_bf16(a.v, b.v, c, 0, 0, 0);
}

// async global->LDS, 16B per lane; LDS dest = wave-uniform base + lane*16
__device__ __forceinline__ void gld_lds16(const ushort* g, ushort* l) {
  __builtin_amdgcn_global_load_lds(
      (__attribute__((address_space(1))) void*)g,
      (__attribute__((address_space(3))) void*)l, 16, 0, 0);
}

// ---------------- casts ----------------
__global__ void cast_x_kernel(const float* __restrict__ src, ushort* __restrict__ dst) {
  int i = blockIdx.x * 256 + threadIdx.x;
  float4 f = ((const float4*)src)[i];
  ushort4 u; u.x = f2bf(f.x); u.y = f2bf(f.y); u.z = f2bf(f.z); u.w = f2bf(f.w);
  ((ushort4*)dst)[i] = u;
}

__global__ void cast_w_kernel(const float* __restrict__ w0, const float* __restrict__ w1,
                              const float* __restrict__ w2, const float* __restrict__ w3,
                              ushort* __restrict__ d0, ushort* __restrict__ d1,
                              ushort* __restrict__ d2, ushort* __restrict__ d3) {
  const float* s; ushort* d;
  int z = blockIdx.y;
  if (z == 0) { s = w0; d = d0; } else if (z == 1) { s = w1; d = d1; }
  else if (z == 2) { s = w2; d = d2; } else { s = w3; d = d3; }
  int i = blockIdx.x * 256 + threadIdx.x;
  float4 f = ((const float4*)s)[i];
  ushort4 u; u.x = f2bf(f.x); u.y = f2bf(f.y); u.z = f2bf(f.z); u.w = f2bf(f.w);
  ((ushort4*)d)[i] = u;
}

// ---------------- 128x128 bt-GEMM, BK=64, XOR-swizzled LDS ----------------
// R8: XCD-chunked blockIdx swizzle (T1). R7 measured gemm0 at 144 MB
// FETCH_SIZE (~4x the unique input) because the 24 blocks sharing an A
// row-panel are round-robined across all 8 XCD L2s. swz groups the grid so
// each XCD owns complete row-panels: all blocks of a panel fill one L2 once.
// nwg%8==0 for both grids -> bijective (ERRATA #11 safe).
// MODE 0: fused QKV.  grid (24,64): wsel picks Wq/Wk/Wv; writes Q (scaled,
//         [B,H,S,HD]) / K ([B,H,S,HD]) / V^T ([B,H,HD,S]).
// MODE 1: out-proj.   grid (8,64): f32 store out[m*DIM+e] + bias[e].
template <int MODE>
__global__ __launch_bounds__(256)
void gemm_bk64(const ushort* __restrict__ A,
               const ushort* __restrict__ B0, const ushort* __restrict__ B1,
               const ushort* __restrict__ B2,
               ushort* __restrict__ Qb, ushort* __restrict__ Kb, ushort* __restrict__ Vtb,
               float* __restrict__ outf, const float* __restrict__ bias, float scaleq) {
  __shared__ __align__(16) ushort As[128 * 64];
  __shared__ __align__(16) ushort Bs[128 * 64];
  const int K = DIM;
  int lane = threadIdx.x & 63, wave = threadIdx.x >> 6;
  int quad = lane >> 4, l15 = lane & 15;

  // --- XCD-chunked swizzle: panel-major work order per XCD chunk
  const int nbx = (MODE == 0) ? 24 : 8;
  int bid = blockIdx.x + blockIdx.y * nbx;     // dispatch order (x fastest)
  const int nwg = nbx * 64;
  int swz = (bid & 7) * (nwg >> 3) + (bid >> 3);  // bijective since nwg%8==0
  int lx = swz % nbx;
  int rowBase = (swz / nbx) * 128;

  int wsel, colBase;
  const ushort* Bt;
  if (MODE == 0) {
    wsel = lx >> 3;
    colBase = (lx & 7) * 128;
    Bt = (wsel == 0) ? B0 : (wsel == 1) ? B1 : B2;
  } else {
    wsel = 0;
    colBase = lx * 128;
    Bt = B0;
  }
  int wm = (wave >> 1) * 64, wn = (wave & 1) * 64;

  const ushort* Ag = A + (size_t)rowBase * K;
  const ushort* Bg = Bt + (size_t)colBase * K;

  f32x4 acc[4][4];
#pragma unroll
  for (int i = 0; i < 4; i++)
#pragma unroll
    for (int j = 0; j < 4; j++) acc[i][j] = (f32x4){0.f, 0.f, 0.f, 0.f};

  for (int k0 = 0; k0 < K; k0 += 64) {
#pragma unroll
    for (int cc = 0; cc < 4; ++cc) {
      int c = wave * 4 + cc;                 // 16 chunks of 64 slots
      int s = c * 64 + lane;                 // 16B slot id in [0,1024)
      int row = s >> 3;
      int c8 = (s & 7) ^ (row & 7);          // swizzled chunk
      gld_lds16(Ag + (size_t)row * K + k0 + c8 * 8, &As[c * 512]);
      gld_lds16(Bg + (size_t)row * K + k0 + c8 * 8, &Bs[c * 512]);
    }
    __syncthreads();
    Frag af[4][2], bf[4][2];
#pragma unroll
    for (int t = 0; t < 4; t++) {
      int ar = wm + t * 16 + l15;
      int br = wn + t * 16 + l15;
#pragma unroll
      for (int kk = 0; kk < 2; kk++) {
        af[t][kk].q = *(const uint4*)&As[ar * 64 + (((kk * 4 + quad) ^ (ar & 7))) * 8];
        bf[t][kk].q = *(const uint4*)&Bs[br * 64 + (((kk * 4 + quad) ^ (br & 7))) * 8];
      }
    }
#pragma unroll
    for (int kk = 0; kk < 2; kk++)
#pragma unroll
      for (int i = 0; i < 4; i++)
#pragma unroll
        for (int j = 0; j < 4; j++) acc[i][j] = mfma16(af[i][kk], bf[j][kk], acc[i][j]);
    __syncthreads();
  }

#pragma unroll
  for (int i = 0; i < 4; i++) {
    int rowt = wm + i * 16 + quad * 4;
#pragma unroll
    for (int j = 0; j < 4; j++) {
      int e = colBase + wn + j * 16 + l15;  // within [0,1024)
      if (MODE == 0) {
        int h = e >> 6, hd = e & 63;
        if (wsel < 2) {
          ushort* dst = wsel ? Kb : Qb;
          float sc = wsel ? 1.f : scaleq;
#pragma unroll
          for (int r = 0; r < 4; r++) {
            int m = rowBase + rowt + r;
            int b = m >> 11, s = m & (S_LEN - 1);
            dst[((size_t)((b * NH + h) * S_LEN + s) << 6) + hd] = f2bf(acc[i][j][r] * sc);
          }
        } else {
          int m0 = rowBase + rowt;
          int b = m0 >> 11, s0 = m0 & (S_LEN - 1);
          ushort4 u;
          u.x = f2bf(acc[i][j][0]); u.y = f2bf(acc[i][j][1]);
          u.z = f2bf(acc[i][j][2]); u.w = f2bf(acc[i][j][3]);
          *(ushort4*)&Vtb[((size_t)((b * NH + h) * HD + hd) << 11) + s0] = u;
        }
      } else {
        float bv = bias[e];
#pragma unroll
        for (int r = 0; r < 4; r++) {
          int m = rowBase + rowt + r;
          outf[(size_t)m * DIM + e] = acc[i][j][r] + bv;
        }
      }
    }
  }
}

// ---------------- flash attention (causal; S^T orientation; no-max streaming softmax) ----------------
// R5's verified kernel (81.6 us measured), unchanged.
//  * de-fused pipeline: 16-MFMA S^T burst -> mask -> exp2/pack burst ->
//    permlane P-redistribution (in-register, zero DS ops) -> PV MFMA burst.
//  * softmax denominator via ones-MFMA (l = P x 1), no VALU reduction.
//  * single-buffered 32 KiB LDS; plain __launch_bounds__(256) (VGPR 124, no
//    spills); bank conflicts measured 0.
//  * bijective balanced qt map {15-yr, 8+yr, 4+yr, 3-yr}.
// grid (B*H, S/128).
__global__ __launch_bounds__(256)
void flash_attn(const ushort* __restrict__ Qb, const ushort* __restrict__ Kb,
                const ushort* __restrict__ Vtb, ushort* __restrict__ Ctx) {
  __shared__ __align__(16) ushort Ks[128 * 64];   // K tile (also Q staging), swizzled
  __shared__ __align__(16) ushort Vs[64 * 128];   // V^T tile, swizzled

  int lane = threadIdx.x & 63, wave = threadIdx.x >> 6;
  int quad = lane >> 4, l15 = lane & 15;
  int bh = blockIdx.x;
  int yq = blockIdx.y >> 2, yr = blockIdx.y & 3;
  int qt = (yq == 0) ? (15 - yr) : (yq == 1) ? (8 + yr) : (yq == 2) ? (4 + yr) : (3 - yr);
  int q0 = qt * 128, wq0 = wave * 32;

  const ushort* Qh = Qb + (size_t)bh * S_LEN * HD;
  const ushort* Kh = Kb + (size_t)bh * S_LEN * HD;
  const ushort* Vh = Vtb + (size_t)bh * HD * S_LEN;

  // ---- stage Q tile (swizzled) into Ks, pull B-frags into registers
#pragma unroll
  for (int cc = 0; cc < 4; ++cc) {
    int c = wave * 4 + cc;
    int s = c * 64 + lane;
    int row = s >> 3;
    int c8 = (s & 7) ^ (row & 7);
    gld_lds16(Qh + (size_t)(q0 + row) * HD + c8 * 8, &Ks[c * 512]);
  }
  __syncthreads();
  Frag qf[2][2];  // B-frag: B[d][qrow]
#pragma unroll
  for (int it = 0; it < 2; ++it)
#pragma unroll
    for (int ks = 0; ks < 2; ++ks) {
      int row = wq0 + it * 16 + l15;
      int c8 = (ks * 4 + quad) ^ (row & 7);
      qf[it][ks].q = *(const uint4*)&Ks[row * 64 + c8 * 8];
    }
  __syncthreads();  // qf readers done before kt=0 staging overwrites Ks

  Frag onesf;  // all-ones bf16 B-frag for the l-via-MFMA trick
  onesf.q = (uint4){0x3F803F80u, 0x3F803F80u, 0x3F803F80u, 0x3F803F80u};

  f32x4 lacc[2];
  f32x4 oacc[2][4];
#pragma unroll
  for (int it = 0; it < 2; ++it) {
    lacc[it] = (f32x4){0.f, 0.f, 0.f, 0.f};
#pragma unroll
    for (int dt = 0; dt < 4; ++dt) oacc[it][dt] = (f32x4){0.f, 0.f, 0.f, 0.f};
  }

  for (int kt = 0; kt <= qt; ++kt) {
    // ---- stage K (8 slots/row) and V^T (16 slots/row), both XOR-swizzled
#pragma unroll
    for (int cc = 0; cc < 4; ++cc) {
      int c = wave * 4 + cc;
      int s = c * 64 + lane;
      int krow = s >> 3, kc8 = (s & 7) ^ (krow & 7);
      int vrow = s >> 4, vc8 = (s & 15) ^ (vrow & 15);
      gld_lds16(Kh + (size_t)(kt * 128 + krow) * HD + kc8 * 8, &Ks[c * 512]);
      gld_lds16(Vh + (size_t)vrow * S_LEN + kt * 128 + vc8 * 8, &Vs[c * 512]);
    }
    __syncthreads();

    // ---- S^T = K · Q^T: pure MFMA burst (16 independent chains, pipelined)
    f32x4 sacc[2][8];
    __builtin_amdgcn_s_setprio(1);
#pragma unroll
    for (int jt = 0; jt < 8; ++jt) {
      int row = jt * 16 + l15;
      Frag kf0, kf1;
      kf0.q = *(const uint4*)&Ks[row * 64 + ((quad ^ (row & 7))) * 8];
      kf1.q = *(const uint4*)&Ks[row * 64 + (((4 + quad) ^ (row & 7))) * 8];
#pragma unroll
      for (int it = 0; it < 2; ++it) {
        f32x4 a = (f32x4){0.f, 0.f, 0.f, 0.f};
        a = mfma16(kf0, qf[it][0], a);
        a = mfma16(kf1, qf[it][1], a);
        sacc[it][jt] = a;
      }
    }
    __builtin_amdgcn_s_setprio(0);

    // ---- causal mask on the diagonal tile only
    if (kt == qt) {
#pragma unroll
      for (int it = 0; it < 2; ++it)
#pragma unroll
        for (int jt = 0; jt < 8; ++jt)
#pragma unroll
          for (int r = 0; r < 4; ++r)
            if (jt * 16 + quad * 4 + r > wq0 + it * 16 + l15)
              sacc[it][jt][r] = -1e30f;
    }

    // ---- exp2 + pack burst (no sum: l comes from the ones-MFMA below)
    uint sw[2][8][2];
#pragma unroll
    for (int it = 0; it < 2; ++it)
#pragma unroll
      for (int jt = 0; jt < 8; ++jt) {
        float p0 = exp2f(sacc[it][jt][0]);
        float p1 = exp2f(sacc[it][jt][1]);
        float p2 = exp2f(sacc[it][jt][2]);
        float p3 = exp2f(sacc[it][jt][3]);
        union { ushort2 h; uint u; } w0, w1;
        w0.h.x = f2bf_n(p0); w0.h.y = f2bf_n(p1);
        w1.h.x = f2bf_n(p2); w1.h.y = f2bf_n(p3);
        sw[it][jt][0] = w0.u;
        sw[it][jt][1] = w1.u;
      }

    // ---- in-register P redistribution: quads exchange at fixed l15.
    // x=[X0 X1 X2 X3] (by quad), y=[Y0..Y3]; after 32-swap: x'=[X0 X1 Y0 Y1],
    // y'=[X2 X3 Y2 Y3]; after 16-swap: x''=[X0 X2 Y0 Y2] (A-frag word u),
    // y''=[X1 X3 Y1 Y3] (A-frag word 2+u).
    Frag pf[2][4];
#pragma unroll
    for (int it = 0; it < 2; ++it)
#pragma unroll
      for (int ks = 0; ks < 4; ++ks) {
        uint x0 = sw[it][2 * ks][0], y0 = sw[it][2 * ks + 1][0];
        uint x1 = sw[it][2 * ks][1], y1 = sw[it][2 * ks + 1][1];
        asm("v_permlane32_swap_b32 %0, %1" : "+v"(x0), "+v"(y0));
        asm("v_permlane16_swap_b32 %0, %1" : "+v"(x0), "+v"(y0));
        asm("v_permlane32_swap_b32 %0, %1" : "+v"(x1), "+v"(y1));
        asm("v_permlane16_swap_b32 %0, %1" : "+v"(x1), "+v"(y1));
        pf[it][ks].q = (uint4){x0, x1, y0, y1};
      }

    // ---- O += P V  and  l += P · 1 (ones-MFMA; V frags shared across its)
    __builtin_amdgcn_s_setprio(1);
#pragma unroll
    for (int dt = 0; dt < 4; ++dt) {
      int row = dt * 16 + l15;
      Frag vf[4];
#pragma unroll
      for (int ks = 0; ks < 4; ++ks)
        vf[ks].q = *(const uint4*)&Vs[row * 128 + (((ks * 4 + quad) ^ (row & 15))) * 8];
#pragma unroll
      for (int it = 0; it < 2; ++it) {
        f32x4 a = oacc[it][dt];
#pragma unroll
        for (int ks = 0; ks < 4; ++ks) a = mfma16(pf[it][ks], vf[ks], a);
        oacc[it][dt] = a;
      }
    }
#pragma unroll
    for (int it = 0; it < 2; ++it) {
      f32x4 a = lacc[it];
#pragma unroll
      for (int ks = 0; ks < 4; ++ks) a = mfma16(pf[it][ks], onesf, a);
      lacc[it] = a;
    }
    __builtin_amdgcn_s_setprio(0);

    __syncthreads();  // all waves done with Ks/Vs before restage
  }

  // ---- epilogue: normalize by l (lacc[it][r] = l[q], uniform over l15)
  int b = bh >> 4, h = bh & 15;
#pragma unroll
  for (int it = 0; it < 2; ++it) {
    float lr[4];
#pragma unroll
    for (int r = 0; r < 4; ++r) lr[r] = 1.f / lacc[it][r];
#pragma unroll
    for (int r = 0; r < 4; ++r) {
      int qg = q0 + wq0 + it * 16 + quad * 4 + r;
      size_t base = ((size_t)(b * S_LEN + qg)) * DIM + h * HD;
#pragma unroll
      for (int dt = 0; dt < 4; ++dt)
        Ctx[base + dt * 16 + l15] = f2bf_n(oacc[it][dt][r] * lr[r]);
    }
  }
}

// ---------------- launch ----------------
extern "C" void kernel_launch(void* const* d_in, const int* in_sizes, int n_in,
                              void* d_out, int out_size, void* d_ws, size_t ws_size,
                              hipStream_t stream) {
  (void)in_sizes; (void)n_in; (void)out_size; (void)ws_size;
  const float* x  = (const float*)d_in[0];
  const float* Wq = (const float*)d_in[1];
  const float* Wk = (const float*)d_in[2];
  const float* Wv = (const float*)d_in[3];
  const float* Wo = (const float*)d_in[4];
  const float* bo = (const float*)d_in[5];
  float* out = (float*)d_out;

  ushort* Xb  = (ushort*)d_ws;                     // [8192][1024]
  ushort* Wqb = Xb  + (size_t)M_ROWS * DIM;
  ushort* Wkb = Wqb + (size_t)DIM * DIM;
  ushort* Wvb = Wkb + (size_t)DIM * DIM;
  ushort* Wob = Wvb + (size_t)DIM * DIM;
  ushort* Qb  = Wob + (size_t)DIM * DIM;           // [B,H,S,HD] (pre-scaled)
  ushort* Kb  = Qb  + (size_t)M_ROWS * DIM;        // [B,H,S,HD]
  ushort* Vtb = Kb  + (size_t)M_ROWS * DIM;        // [B,H,HD,S]
  ushort* Ctx = Vtb + (size_t)M_ROWS * DIM;        // [B,S,D]

  const float SCALE_Q = 0.18033688011112042f;  // log2(e) / sqrt(HD)

  cast_x_kernel<<<dim3(M_ROWS * DIM / 1024), 256, 0, stream>>>(x, Xb);
  cast_w_kernel<<<dim3(DIM * DIM / 1024, 4), 256, 0, stream>>>(Wq, Wk, Wv, Wo, Wqb, Wkb, Wvb, Wob);

  gemm_bk64<0><<<dim3(24, 64), 256, 0, stream>>>(Xb, Wqb, Wkb, Wvb, Qb, Kb, Vtb,
                                                 nullptr, nullptr, SCALE_Q);

  flash_attn<<<dim3(BATCH * NH, S_LEN / 128), 256, 0, stream>>>(Qb, Kb, Vtb, Ctx);

  gemm_bk64<1><<<dim3(8, 64), 256, 0, stream>>>(Ctx, Wob, nullptr, nullptr, nullptr, nullptr,
                                                nullptr, out, bo, 1.0f);
}